// Round 5
// baseline (246.123 us; speedup 1.0000x reference)
//
#include <hip/hip_runtime.h>

#define NB 256
#define NT 1024
#define NL 64

typedef __fp16 h2v __attribute__((ext_vector_type(2)));

__device__ __forceinline__ float rfl_f(float v) {
  return __builtin_bit_cast(float, __builtin_amdgcn_readfirstlane(__builtin_bit_cast(int, v)));
}

// partner = value from lane^1, via DPP quad_perm [1,0,3,2] (VALU, no LDS pipe)
__device__ __forceinline__ float dpp_xor1(float v) {
  int i = __builtin_bit_cast(int, v);
  int r = __builtin_amdgcn_update_dpp(i, i, 0xB1, 0xF, 0xF, false);
  return __builtin_bit_cast(float, r);
}

// Phase 1: pack (w, partner) -> f16x2, write one b32 to this chain's LDS
// buffer, issue the 8 uniform-address (broadcast) b128 reads. P0..P7 stay
// live for phase 2. Two chains' phase-1/phase-2 interleave so each chain's
// LDS round-trip latency is covered by the other chain's work.
#define CRF_BCAST(PFX, W, LB, LBV)                                            \
  float PFX##wn = dpp_xor1(W);                                                \
  h2v PFX##pk = __builtin_amdgcn_cvt_pkrtz(W, PFX##wn);                       \
  LB[slot] = __builtin_bit_cast(int, PFX##pk);                                \
  int4 PFX##P0 = LBV[0], PFX##P1 = LBV[1], PFX##P2 = LBV[2], PFX##P3 = LBV[3];\
  int4 PFX##P4 = LBV[4], PFX##P5 = LBV[5], PFX##P6 = LBV[6], PFX##P7 = LBV[7];

#define DOT4P(PFX, P, B, RT)                                                  \
  PFX##s0 = __builtin_amdgcn_fdot2(__builtin_bit_cast(h2v, (P).x), RT[(B) + 0], PFX##s0, false); \
  PFX##s1 = __builtin_amdgcn_fdot2(__builtin_bit_cast(h2v, (P).y), RT[(B) + 1], PFX##s1, false); \
  PFX##s2 = __builtin_amdgcn_fdot2(__builtin_bit_cast(h2v, (P).z), RT[(B) + 2], PFX##s2, false); \
  PFX##s3 = __builtin_amdgcn_fdot2(__builtin_bit_cast(h2v, (P).w), RT[(B) + 3], PFX##s3, false);

// Phase 2: uniform renorm scale K = 2^(3-e5) from pair0's f16 exponent
// (pure VALU, no readfirstlane), 32 fdot2, state update. e2 accumulates raw
// e5; the -3/step is folded in once at the end.
#define CRF_MATVEC(PFX, W, E2, RT, EF)                                        \
  int PFX##e5 = (PFX##P0.x >> 10) & 0x1f;                                     \
  float PFX##K = __builtin_bit_cast(float, (130 - PFX##e5) << 23);            \
  E2 += PFX##e5;                                                              \
  float PFX##s0 = 0.f, PFX##s1 = 0.f, PFX##s2 = 0.f, PFX##s3 = 0.f;           \
  DOT4P(PFX, PFX##P0, 0, RT) DOT4P(PFX, PFX##P1, 4, RT)                       \
  DOT4P(PFX, PFX##P2, 8, RT) DOT4P(PFX, PFX##P3, 12, RT)                      \
  DOT4P(PFX, PFX##P4, 16, RT) DOT4P(PFX, PFX##P5, 20, RT)                     \
  DOT4P(PFX, PFX##P6, 24, RT) DOT4P(PFX, PFX##P7, 28, RT)                     \
  W = ((PFX##s0 + PFX##s1) + (PFX##s2 + PFX##s3)) * (PFX##K * (EF));

#define STEP_PAIR(EFF, EFB)                                                   \
  {                                                                           \
    CRF_BCAST(F_, wF, lbF, lbvF)                                              \
    CRF_BCAST(B_, wB, lbB, lbvB)                                              \
    CRF_MATVEC(F_, wF, e2F, Rf, EFF)                                          \
    CRF_MATVEC(B_, wB, e2B, Rb, EFB)                                          \
  }

// Blocks 0..255: fused fwd+bwd chains of batch b (2 independent recurrences
// per wave -> software TLP hides the LDS round-trip). Blocks 256..511: gold.
__global__ __launch_bounds__(64, 1) void fb_kernel(const float* __restrict__ scores,
                                                   const int* __restrict__ targets,
                                                   const float* __restrict__ start,
                                                   const float* __restrict__ Tm,
                                                   const float* __restrict__ endv,
                                                   float* __restrict__ wsA,
                                                   float* __restrict__ wsB,
                                                   float* __restrict__ wsG) {
  const int lane = threadIdx.x;
  const int bb = blockIdx.x;

  if (bb >= NB) {  // ---- gold path: one wave per batch ----
    const int b = bb - NB;
    const int* tg = targets + b * NT;
    const float* sc = scores + (size_t)b * NT * NL;
    float acc = 0.f;
    for (int t = lane; t < NT; t += 64) {
      int c = tg[t];
      acc += sc[t * NL + c];
      if (t > 0) acc += Tm[c * NL + tg[t - 1]];  // T_mat[cur, prev]
    }
#pragma unroll
    for (int off = 32; off > 0; off >>= 1) acc += __shfl_xor(acc, off, 64);
    if (lane == 0) wsG[b] = acc + start[tg[0]] + endv[tg[NT - 1]];
    return;
  }

  __shared__ int4 lds_s[32];        // words 0..63 = F buffer, 64..127 = B buffer
  int* lbF = (int*)lds_s;
  int* lbB = (int*)(lds_s + 16);
  const int4* lbvF = lds_s;
  const int4* lbvB = lds_s + 16;
  const int slot = (lane & 1) * 32 + (lane >> 1);  // 2 lanes/bank write -> free

  const int b = bb;
  const float* sc = scores + (size_t)b * NT * NL;
  const float LN2 = 0.69314718055994530942f;

  // f16x2 transition tables: Rf[k] = (exp(T[lane][2k]), exp(T[lane][2k+1]))
  //                          Rb[k] = (exp(T[2k][lane]), exp(T[2k+1][lane]))
  h2v Rf[32], Rb[32];
#pragma unroll
  for (int k = 0; k < 32; k++) {
    Rf[k] = __builtin_amdgcn_cvt_pkrtz(__expf(Tm[lane * NL + 2 * k]),
                                       __expf(Tm[lane * NL + 2 * k + 1]));
    Rb[k] = __builtin_amdgcn_cvt_pkrtz(__expf(Tm[(2 * k) * NL + lane]),
                                       __expf(Tm[(2 * k + 1) * NL + lane]));
  }

  float aF = start[lane] + sc[lane];              // alpha_0
  float mF = rfl_f(aF);
  float wF = __expf(aF - mF) * 16.f;
  int e2F = -4;

  float aB = endv[lane] + sc[(NT - 1) * NL + lane];  // q_1023
  float mB = rfl_f(aB);
  float wB = __expf(aB - mB) * 16.f;
  int e2B = -4;

  float bufF[4], bufB[4];
#pragma unroll
  for (int k = 0; k < 4; k++) {
    bufF[k] = sc[(1 + k) * NL + lane];
    bufB[k] = sc[(1022 - k) * NL + lane];
  }

  for (int i = 0; i < 127; i++) {  // F: t = 1..508, B: te = 1022..515
    float nbF[4], nbB[4];
    int tf = 5 + 4 * i, tb = 1018 - 4 * i;  // prefetch (509..512 / 514..511 at i=126)
#pragma unroll
    for (int k = 0; k < 4; k++) {
      nbF[k] = sc[(tf + k) * NL + lane];
      nbB[k] = sc[(tb - k) * NL + lane];
    }
    float EvF[4], EvB[4];
#pragma unroll
    for (int k = 0; k < 4; k++) {
      EvF[k] = __expf(bufF[k]);  // off critical chain
      EvB[k] = __expf(bufB[k]);
    }
    STEP_PAIR(EvF[0], EvB[0])
    STEP_PAIR(EvF[1], EvB[1])
    STEP_PAIR(EvF[2], EvB[2])
    STEP_PAIR(EvF[3], EvB[3])
#pragma unroll
    for (int k = 0; k < 4; k++) {
      bufF[k] = nbF[k];
      bufB[k] = nbB[k];
    }
  }

  // tails: bufF = emits t=509..512; bufB = emits te=514,513,(512,511 unused)
  {
    float EvF0 = __expf(bufF[0]), EvF1 = __expf(bufF[1]);
    float EvF2 = __expf(bufF[2]), EvF3 = __expf(bufF[3]);
    float EvB0 = __expf(bufB[0]), EvB1 = __expf(bufB[1]);
    STEP_PAIR(EvF0, EvB0)
    STEP_PAIR(EvF1, EvB1)
    STEP_PAIR(EvF2, 1.0f)  // B final matvec-only step -> beta_512
    {
      CRF_BCAST(F_, wF, lbF, lbvF)
      CRF_MATVEC(F_, wF, e2F, Rf, EvF3)
    }
  }

  // F: 512 steps, B: 511 steps; fold the per-step -3 into the ledger here.
  wsA[lane * NB + b] = mF + (float)(e2F - 3 * 512) * LN2 + __logf(wF);  // alpha_512
  wsB[lane * NB + b] = mB + (float)(e2B - 3 * 511) * LN2 + __logf(wB);  // beta_512
}

// thread b handles batch b: lse over 64 states (coalesced via transposed ws layout),
// subtract gold, block-reduce mean.
__global__ __launch_bounds__(256) void combine_kernel(const float* __restrict__ wsA,
                                                      const float* __restrict__ wsB,
                                                      const float* __restrict__ wsG,
                                                      float* __restrict__ out) {
  const int b = threadIdx.x;
  float m = -INFINITY;
#pragma unroll
  for (int j = 0; j < NL; j++) m = fmaxf(m, wsA[j * NB + b] + wsB[j * NB + b]);
  float s = 0.f;
#pragma unroll
  for (int j = 0; j < NL; j++) s += __expf(wsA[j * NB + b] + wsB[j * NB + b] - m);
  float loss = (m + __logf(s)) - wsG[b];
#pragma unroll
  for (int off = 32; off > 0; off >>= 1) loss += __shfl_xor(loss, off, 64);
  __shared__ float red[4];
  if ((b & 63) == 0) red[b >> 6] = loss;
  __syncthreads();
  if (b == 0) out[0] = (red[0] + red[1] + red[2] + red[3]) * (1.0f / NB);
}

extern "C" void kernel_launch(void* const* d_in, const int* in_sizes, int n_in,
                              void* d_out, int out_size, void* d_ws, size_t ws_size,
                              hipStream_t stream) {
  const float* scores = (const float*)d_in[0];
  const int* targets = (const int*)d_in[1];
  const float* start = (const float*)d_in[2];
  const float* Tm = (const float*)d_in[3];
  const float* endv = (const float*)d_in[4];
  float* out = (float*)d_out;

  float* wsA = (float*)d_ws;       // [NL*NB] alpha_512, transposed [state][batch]
  float* wsB = wsA + NB * NL;      // [NL*NB] beta_512, transposed
  float* wsG = wsB + NB * NL;      // [NB] gold path scores

  fb_kernel<<<2 * NB, 64, 0, stream>>>(scores, targets, start, Tm, endv, wsA, wsB, wsG);
  combine_kernel<<<1, 256, 0, stream>>>(wsA, wsB, wsG, out);
}